// Round 7
// baseline (1264.526 us; speedup 1.0000x reference)
//
#include <hip/hip_runtime.h>
#include <stdint.h>
#include <stddef.h>

#define D 48
#define BLK 256
#define BSH 9                 // bucket = row >> 9 (512 rows/bucket)

// ---------------- JAX threefry2x32 (20 rounds), constexpr so keys fold ----------------
struct U2 { uint32_t a, b; };

__host__ __device__ constexpr U2 tf2x32(uint32_t k0, uint32_t k1, uint32_t c0, uint32_t c1) {
  uint32_t ks2 = k0 ^ k1 ^ 0x1BD11BDAu;
  uint32_t x0 = c0 + k0, x1 = c1 + k1;
#define TFR(r) x0 += x1; x1 = (x1 << (r)) | (x1 >> (32 - (r))); x1 ^= x0;
  TFR(13) TFR(15) TFR(26) TFR(6)
  x0 += k1; x1 += ks2 + 1u;
  TFR(17) TFR(29) TFR(16) TFR(24)
  x0 += ks2; x1 += k0 + 2u;
  TFR(13) TFR(15) TFR(26) TFR(6)
  x0 += k0; x1 += k1 + 3u;
  TFR(17) TFR(29) TFR(16) TFR(24)
  x0 += k1; x1 += ks2 + 4u;
  TFR(13) TFR(15) TFR(26) TFR(6)
  x0 += ks2; x1 += k0 + 5u;
#undef TFR
  return U2{x0, x1};
}

// cm = col | (mask5 << 20); col < 2^20 (N = 100K), mask bit i = kept in iter i
struct __align__(8) Edge { uint32_t cm; float val; };

__global__ __launch_bounds__(BLK) void k_mask_hist(
    const int* __restrict__ erow, unsigned char* __restrict__ maskb,
    int* __restrict__ cnt, int E) {
  int j = blockIdx.x * BLK + threadIdx.x;
  if (j >= E) return;
  constexpr U2 K0 = tf2x32(0u, 42u, 0u, 0u);
  constexpr U2 K1 = tf2x32(0u, 42u, 0u, 1u);
  constexpr U2 K2 = tf2x32(0u, 42u, 0u, 2u);
  constexpr U2 K3 = tf2x32(0u, 42u, 0u, 3u);
  constexpr U2 K4 = tf2x32(0u, 42u, 0u, 4u);
  uint32_t uj = (uint32_t)j;
  unsigned m = 0;
  U2 r;
  r = tf2x32(K0.a, K0.b, 0u, uj); m |= ((((r.a ^ r.b) >> 31) ^ 1u) << 0);
  r = tf2x32(K1.a, K1.b, 0u, uj); m |= ((((r.a ^ r.b) >> 31) ^ 1u) << 1);
  r = tf2x32(K2.a, K2.b, 0u, uj); m |= ((((r.a ^ r.b) >> 31) ^ 1u) << 2);
  r = tf2x32(K3.a, K3.b, 0u, uj); m |= ((((r.a ^ r.b) >> 31) ^ 1u) << 3);
  r = tf2x32(K4.a, K4.b, 0u, uj); m |= ((((r.a ^ r.b) >> 31) ^ 1u) << 4);
  maskb[j] = (unsigned char)m;
  atomicAdd(&cnt[erow[j]], 1);
}

__global__ __launch_bounds__(BLK) void k_block_sum(const int* __restrict__ cnt,
                                                   int* __restrict__ bsum, int N) {
  int i = blockIdx.x * BLK + threadIdx.x;
  int v = (i < N) ? cnt[i] : 0;
  for (int off = 32; off > 0; off >>= 1) v += __shfl_down(v, off, 64);
  __shared__ int s[BLK / 64];
  if ((threadIdx.x & 63) == 0) s[threadIdx.x >> 6] = v;
  __syncthreads();
  if (threadIdx.x == 0) {
    int t = 0;
    for (int w = 0; w < BLK / 64; ++w) t += s[w];
    bsum[blockIdx.x] = t;
  }
}

// bucket counts from row counts: block b (64 thr) sums cnt[b<<BSH .. +(1<<BSH))
__global__ __launch_bounds__(64) void k_bkt_cnt(const int* __restrict__ cnt,
                                                int* __restrict__ bkt, int N) {
  int base = blockIdx.x << BSH;
  int v = 0;
  for (int i = threadIdx.x; i < (1 << BSH); i += 64) {
    int r = base + i;
    if (r < N) v += cnt[r];
  }
  for (int off = 32; off > 0; off >>= 1) v += __shfl_down(v, off, 64);
  if (threadIdx.x == 0) bkt[blockIdx.x] = v;
}

// grid=2: block 0 scans a[0..na), block 1 scans b[0..nb) and copies to bcur
__global__ __launch_bounds__(512) void k_scan2(int* __restrict__ a, int na,
                                               int* __restrict__ b, int nb,
                                               int* __restrict__ bcur) {
  int* arr = blockIdx.x ? b : a;
  int n    = blockIdx.x ? nb : na;
  __shared__ int s[512];
  int t = threadIdx.x;
  int v = (t < n) ? arr[t] : 0;
  s[t] = v;
  __syncthreads();
  for (int off = 1; off < 512; off <<= 1) {
    int u = (t >= off) ? s[t - off] : 0;
    __syncthreads();
    s[t] += u;
    __syncthreads();
  }
  if (t < n) {
    int excl = (t == 0) ? 0 : s[t - 1];
    arr[t] = excl;
    if (blockIdx.x) bcur[t] = excl;
  }
}

__global__ __launch_bounds__(BLK) void k_write_rowptr(
    const int* __restrict__ cnt, const int* __restrict__ boff,
    int* __restrict__ row_ptr, int* __restrict__ cursor, int N, int E) {
  __shared__ int s[BLK];
  int t = threadIdx.x;
  int i = blockIdx.x * BLK + t;
  int v = (i < N) ? cnt[i] : 0;
  s[t] = v;
  __syncthreads();
  for (int off = 1; off < BLK; off <<= 1) {
    int u = (t >= off) ? s[t - off] : 0;
    __syncthreads();
    s[t] += u;
    __syncthreads();
  }
  if (i < N) {
    int excl = s[t] - v + boff[blockIdx.x];
    row_ptr[i] = excl;
    cursor[i] = excl;
  }
  if (i == 0) row_ptr[N] = E;
}

// Pass A: partition edges by bucket (row>>BSH). Frontier lines per bucket stay
// L2-hot (an append every ~196 stream edges) -> write traffic ~= payload.
__global__ __launch_bounds__(BLK) void k_bucket_scatter(
    const int* __restrict__ erow, const int* __restrict__ ecol,
    const float* __restrict__ eval, const unsigned char* __restrict__ maskb,
    int* __restrict__ bcur, Edge* __restrict__ es_b, int* __restrict__ rowb,
    int E) {
  int j = blockIdx.x * BLK + threadIdx.x;
  if (j >= E) return;
  int row = erow[j];
  Edge eg;
  eg.cm  = (uint32_t)ecol[j] | ((uint32_t)maskb[j] << 20);
  eg.val = eval[j] * 2.0f;  // 1/keep = 2
  int p = atomicAdd(&bcur[row >> BSH], 1);
  es_b[p] = eg;
  rowb[p] = row;
}

// Pass B: exact CSR scatter on bucket-sorted stream. Rows clustered in 512-row
// windows -> cursor + destination lines hot -> write traffic ~= payload.
__global__ __launch_bounds__(BLK) void k_final_scatter(
    const Edge* __restrict__ es_b, const int* __restrict__ rowb,
    int* __restrict__ cursor, Edge* __restrict__ es, int E) {
  int j = blockIdx.x * BLK + threadIdx.x;
  if (j >= E) return;
  Edge eg = es_b[j];
  int p = atomicAdd(&cursor[rowb[j]], 1);
  es[p] = eg;
}

// 4 rows per wave: 16 lanes/row, each lane owns 3 features.
// Branchless, unroll-8: dropped/OOB edges gather row 0 of x (L1-hot) with val=0.
__global__ __launch_bounds__(BLK) void k_spmm(
    const int* __restrict__ row_ptr, const Edge* __restrict__ es,
    const float* __restrict__ x, const float* __restrict__ logits,
    float* __restrict__ xn, int N, int iter) {
  int t = blockIdx.x * BLK + threadIdx.x;
  int r = t >> 4;            // 16 threads per row
  if (r >= N) return;
  int sl = t & 15;
  int s = row_ptr[r], e = row_ptr[r + 1];
  float a0 = 0.f, a1 = 0.f, a2 = 0.f;
  const float* xb = x + 3 * sl;
  const unsigned shift = 20u + (unsigned)iter;
  for (int k = s; k < e; k += 8) {
#pragma unroll
    for (int i = 0; i < 8; ++i) {
      int kk = k + i;
      // OOB reads (≤7 elems past row end) stay inside d_ws slack; zeroed by `in`.
      bool in = kk < e;
      Edge eg = es[kk];
      bool bit = in && ((eg.cm >> shift) & 1u);
      int c = bit ? (int)(eg.cm & 0xFFFFFu) : 0;
      float v = bit ? eg.val : 0.0f;
      const float* xp = xb + (size_t)c * D;
      a0 = fmaf(v, xp[0], a0);
      a1 = fmaf(v, xp[1], a1);
      a2 = fmaf(v, xp[2], a2);
    }
  }
  size_t o = (size_t)r * D + 3 * sl;
  xn[o + 0] = 0.85f * a0 + 0.15f * logits[o + 0];
  xn[o + 1] = 0.85f * a1 + 0.15f * logits[o + 1];
  xn[o + 2] = 0.85f * a2 + 0.15f * logits[o + 2];
}

extern "C" void kernel_launch(void* const* d_in, const int* in_sizes, int n_in,
                              void* d_out, int out_size, void* d_ws, size_t ws_size,
                              hipStream_t stream) {
  const float* logits   = (const float*)d_in[0];
  const float* edge_val = (const float*)d_in[1];
  const int*   edge_row = (const int*)d_in[2];
  const int*   edge_col = (const int*)d_in[3];
  float* out = (float*)d_out;

  const int E = in_sizes[1];
  const int N = in_sizes[0] / D;
  const int NB   = (N + BLK - 1) / BLK;
  const int EB   = (E + BLK - 1) / BLK;
  const int NBKT = (N + (1 << BSH) - 1) >> BSH;   // 196 for N=100K

  char* p = (char*)d_ws;
  auto alloc = [&](size_t bytes) {
    char* q = p;
    p += (bytes + 255) & ~(size_t)255;
    return q;
  };
  int* cnt              = (int*)alloc((size_t)N * 4);
  int* row_ptr          = (int*)alloc((size_t)(N + 1) * 4);
  int* cursor           = (int*)alloc((size_t)N * 4);
  int* boff             = (int*)alloc((size_t)NB * 4);
  int* bkt              = (int*)alloc((size_t)NBKT * 4);
  int* bcur             = (int*)alloc((size_t)NBKT * 4);
  unsigned char* maskb  = (unsigned char*)alloc((size_t)E);
  Edge* es              = (Edge*)alloc((size_t)E * 8 + 64);  // +slack for OOB unroll reads
  // union: {es_b + rowb} (build phase) overlap xA (spmm phase; first written iter 2)
  size_t un_sz = (size_t)E * 12 + 512;
  size_t xa_sz = (size_t)N * D * 4;
  char* un = alloc(un_sz > xa_sz ? un_sz : xa_sz);
  Edge* es_b = (Edge*)un;
  int*  rowb = (int*)(un + (((size_t)E * 8 + 255) & ~(size_t)255));
  float* xA  = (float*)un;

  hipMemsetAsync(cnt, 0, (size_t)N * 4, stream);
  k_mask_hist<<<EB, BLK, 0, stream>>>(edge_row, maskb, cnt, E);
  k_block_sum<<<NB, BLK, 0, stream>>>(cnt, boff, N);
  k_bkt_cnt<<<NBKT, 64, 0, stream>>>(cnt, bkt, N);
  k_scan2<<<2, 512, 0, stream>>>(boff, NB, bkt, NBKT, bcur);
  k_write_rowptr<<<NB, BLK, 0, stream>>>(cnt, boff, row_ptr, cursor, N, E);
  k_bucket_scatter<<<EB, BLK, 0, stream>>>(edge_row, edge_col, edge_val, maskb,
                                           bcur, es_b, rowb, E);
  k_final_scatter<<<EB, BLK, 0, stream>>>(es_b, rowb, cursor, es, E);

  const int RPB = BLK / 16;  // rows per block
  const float* src = logits;
  float* dst = out;
  for (int i = 0; i < 5; ++i) {
    k_spmm<<<(N + RPB - 1) / RPB, BLK, 0, stream>>>(row_ptr, es,
                                                    src, logits, dst, N, i);
    src = dst;
    dst = (dst == out) ? xA : out;
  }
}

// Round 8
// 386.711 us; speedup vs baseline: 3.2700x; 3.2700x over previous
//
#include <hip/hip_runtime.h>
#include <stdint.h>
#include <stddef.h>

#define D 48
#define BLK 256
#define BSH 9                 // bucket = row >> 9 (512 rows/bucket)
#define NBKT_MAX 256
#define EPT 16                // edges per thread in multisplit
#define CHUNK (BLK * EPT)     // 4096 edges per block

// ---------------- JAX threefry2x32 (20 rounds), constexpr so keys fold ----------------
struct U2 { uint32_t a, b; };

__host__ __device__ constexpr U2 tf2x32(uint32_t k0, uint32_t k1, uint32_t c0, uint32_t c1) {
  uint32_t ks2 = k0 ^ k1 ^ 0x1BD11BDAu;
  uint32_t x0 = c0 + k0, x1 = c1 + k1;
#define TFR(r) x0 += x1; x1 = (x1 << (r)) | (x1 >> (32 - (r))); x1 ^= x0;
  TFR(13) TFR(15) TFR(26) TFR(6)
  x0 += k1; x1 += ks2 + 1u;
  TFR(17) TFR(29) TFR(16) TFR(24)
  x0 += ks2; x1 += k0 + 2u;
  TFR(13) TFR(15) TFR(26) TFR(6)
  x0 += k0; x1 += k1 + 3u;
  TFR(17) TFR(29) TFR(16) TFR(24)
  x0 += k1; x1 += ks2 + 4u;
  TFR(13) TFR(15) TFR(26) TFR(6)
  x0 += ks2; x1 += k0 + 5u;
#undef TFR
  return U2{x0, x1};
}

// cm = col | (mask5 << 20); col < 2^20 (N = 100K), mask bit i = kept in iter i
struct __align__(8) Edge { uint32_t cm; float val; };

__global__ __launch_bounds__(BLK) void k_mask_hist(
    const int* __restrict__ erow, unsigned char* __restrict__ maskb,
    int* __restrict__ cnt, int E) {
  int j = blockIdx.x * BLK + threadIdx.x;
  if (j >= E) return;
  constexpr U2 K0 = tf2x32(0u, 42u, 0u, 0u);
  constexpr U2 K1 = tf2x32(0u, 42u, 0u, 1u);
  constexpr U2 K2 = tf2x32(0u, 42u, 0u, 2u);
  constexpr U2 K3 = tf2x32(0u, 42u, 0u, 3u);
  constexpr U2 K4 = tf2x32(0u, 42u, 0u, 4u);
  uint32_t uj = (uint32_t)j;
  unsigned m = 0;
  U2 r;
  r = tf2x32(K0.a, K0.b, 0u, uj); m |= ((((r.a ^ r.b) >> 31) ^ 1u) << 0);
  r = tf2x32(K1.a, K1.b, 0u, uj); m |= ((((r.a ^ r.b) >> 31) ^ 1u) << 1);
  r = tf2x32(K2.a, K2.b, 0u, uj); m |= ((((r.a ^ r.b) >> 31) ^ 1u) << 2);
  r = tf2x32(K3.a, K3.b, 0u, uj); m |= ((((r.a ^ r.b) >> 31) ^ 1u) << 3);
  r = tf2x32(K4.a, K4.b, 0u, uj); m |= ((((r.a ^ r.b) >> 31) ^ 1u) << 4);
  maskb[j] = (unsigned char)m;
  atomicAdd(&cnt[erow[j]], 1);
}

__global__ __launch_bounds__(BLK) void k_block_sum(const int* __restrict__ cnt,
                                                   int* __restrict__ bsum, int N) {
  int i = blockIdx.x * BLK + threadIdx.x;
  int v = (i < N) ? cnt[i] : 0;
  for (int off = 32; off > 0; off >>= 1) v += __shfl_down(v, off, 64);
  __shared__ int s[BLK / 64];
  if ((threadIdx.x & 63) == 0) s[threadIdx.x >> 6] = v;
  __syncthreads();
  if (threadIdx.x == 0) {
    int t = 0;
    for (int w = 0; w < BLK / 64; ++w) t += s[w];
    bsum[blockIdx.x] = t;
  }
}

// bucket counts from row counts: block b (64 thr) sums cnt[b<<BSH .. +(1<<BSH))
__global__ __launch_bounds__(64) void k_bkt_cnt(const int* __restrict__ cnt,
                                                int* __restrict__ bkt, int N) {
  int base = blockIdx.x << BSH;
  int v = 0;
  for (int i = threadIdx.x; i < (1 << BSH); i += 64) {
    int r = base + i;
    if (r < N) v += cnt[r];
  }
  for (int off = 32; off > 0; off >>= 1) v += __shfl_down(v, off, 64);
  if (threadIdx.x == 0) bkt[blockIdx.x] = v;
}

// grid=2: block 0 scans boff[0..na); block 1 scans bkt[0..nb) (exclusive, in
// place -> bkt becomes bucket offsets) and copies to bcur (pass-A cursors).
__global__ __launch_bounds__(512) void k_scan2(int* __restrict__ a, int na,
                                               int* __restrict__ b, int nb,
                                               int* __restrict__ bcur) {
  int* arr = blockIdx.x ? b : a;
  int n    = blockIdx.x ? nb : na;
  __shared__ int s[512];
  int t = threadIdx.x;
  int v = (t < n) ? arr[t] : 0;
  s[t] = v;
  __syncthreads();
  for (int off = 1; off < 512; off <<= 1) {
    int u = (t >= off) ? s[t - off] : 0;
    __syncthreads();
    s[t] += u;
    __syncthreads();
  }
  if (t < n) {
    int excl = (t == 0) ? 0 : s[t - 1];
    arr[t] = excl;
    if (blockIdx.x) bcur[t] = excl;
  }
}

__global__ __launch_bounds__(BLK) void k_write_rowptr(
    const int* __restrict__ cnt, const int* __restrict__ boff,
    int* __restrict__ row_ptr, int N, int E) {
  __shared__ int s[BLK];
  int t = threadIdx.x;
  int i = blockIdx.x * BLK + t;
  int v = (i < N) ? cnt[i] : 0;
  s[t] = v;
  __syncthreads();
  for (int off = 1; off < BLK; off <<= 1) {
    int u = (t >= off) ? s[t - off] : 0;
    __syncthreads();
    s[t] += u;
    __syncthreads();
  }
  if (i < N) row_ptr[i] = s[t] - v + boff[blockIdx.x];
  if (i == 0) row_ptr[N] = E;
}

// Pass A: LDS-multisplit bucket partition. Each block reserves one run per
// bucket with ONE global atomic (77K total, ~400/addr: no contention), then
// scatters into block-exclusive runs (lines filled while L2-hot).
__global__ __launch_bounds__(BLK) void k_bucket_ms(
    const int* __restrict__ erow, const int* __restrict__ ecol,
    const float* __restrict__ eval, const unsigned char* __restrict__ maskb,
    int* __restrict__ bcur, Edge* __restrict__ es_b, int* __restrict__ rowb,
    int E, int nbkt) {
  __shared__ int h[NBKT_MAX];
  __shared__ int base[NBKT_MAX];
  int t = threadIdx.x;
  int j0 = blockIdx.x * CHUNK;
  for (int i = t; i < nbkt; i += BLK) h[i] = 0;
  __syncthreads();
#pragma unroll
  for (int k = 0; k < EPT; ++k) {
    int j = j0 + k * BLK + t;
    if (j < E) atomicAdd(&h[erow[j] >> BSH], 1);
  }
  __syncthreads();
  for (int i = t; i < nbkt; i += BLK)
    base[i] = h[i] ? atomicAdd(&bcur[i], h[i]) : 0;
  __syncthreads();
  for (int i = t; i < nbkt; i += BLK) h[i] = 0;
  __syncthreads();
#pragma unroll
  for (int k = 0; k < EPT; ++k) {
    int j = j0 + k * BLK + t;
    if (j >= E) continue;
    int row = erow[j];
    int b = row >> BSH;
    int slot = atomicAdd(&h[b], 1);
    int p = base[b] + slot;
    Edge eg;
    eg.cm  = (uint32_t)ecol[j] | ((uint32_t)maskb[j] << 20);
    eg.val = eval[j] * 2.0f;  // 1/keep = 2
    es_b[p] = eg;
    rowb[p] = row;
  }
}

// Pass B: one block per bucket; 512 row-cursors in LDS (zero global atomics).
// All writes land in the bucket's private 64KB CSR window -> full lines.
__global__ __launch_bounds__(BLK) void k_final_scatter(
    const Edge* __restrict__ es_b, const int* __restrict__ rowb,
    const int* __restrict__ bkt_off, const int* __restrict__ row_ptr,
    Edge* __restrict__ es, int E) {
  __shared__ int lcur[1 << BSH];
  int b = blockIdx.x;
  int t = threadIdx.x;
  int s = bkt_off[b];
  int e = (b == (int)gridDim.x - 1) ? E : bkt_off[b + 1];
  int rbase = b << BSH;
  for (int i = t; i < (1 << BSH); i += BLK) lcur[i] = 0;
  __syncthreads();
  for (int j = s + t; j < e; j += BLK) {
    int row = rowb[j];
    int slot = atomicAdd(&lcur[row - rbase], 1);
    es[row_ptr[row] + slot] = es_b[j];
  }
}

// 4 rows per wave: 16 lanes/row, each lane owns 3 features.
// Branchless, unroll-8: dropped/OOB edges gather row 0 of x (L1-hot) with val=0.
__global__ __launch_bounds__(BLK) void k_spmm(
    const int* __restrict__ row_ptr, const Edge* __restrict__ es,
    const float* __restrict__ x, const float* __restrict__ logits,
    float* __restrict__ xn, int N, int iter) {
  int t = blockIdx.x * BLK + threadIdx.x;
  int r = t >> 4;            // 16 threads per row
  if (r >= N) return;
  int sl = t & 15;
  int s = row_ptr[r], e = row_ptr[r + 1];
  float a0 = 0.f, a1 = 0.f, a2 = 0.f;
  const float* xb = x + 3 * sl;
  const unsigned shift = 20u + (unsigned)iter;
  for (int k = s; k < e; k += 8) {
#pragma unroll
    for (int i = 0; i < 8; ++i) {
      int kk = k + i;
      // OOB reads (≤7 elems past row end) stay inside d_ws slack; zeroed by `in`.
      bool in = kk < e;
      Edge eg = es[kk];
      bool bit = in && ((eg.cm >> shift) & 1u);
      int c = bit ? (int)(eg.cm & 0xFFFFFu) : 0;
      float v = bit ? eg.val : 0.0f;
      const float* xp = xb + (size_t)c * D;
      a0 = fmaf(v, xp[0], a0);
      a1 = fmaf(v, xp[1], a1);
      a2 = fmaf(v, xp[2], a2);
    }
  }
  size_t o = (size_t)r * D + 3 * sl;
  xn[o + 0] = 0.85f * a0 + 0.15f * logits[o + 0];
  xn[o + 1] = 0.85f * a1 + 0.15f * logits[o + 1];
  xn[o + 2] = 0.85f * a2 + 0.15f * logits[o + 2];
}

extern "C" void kernel_launch(void* const* d_in, const int* in_sizes, int n_in,
                              void* d_out, int out_size, void* d_ws, size_t ws_size,
                              hipStream_t stream) {
  const float* logits   = (const float*)d_in[0];
  const float* edge_val = (const float*)d_in[1];
  const int*   edge_row = (const int*)d_in[2];
  const int*   edge_col = (const int*)d_in[3];
  float* out = (float*)d_out;

  const int E = in_sizes[1];
  const int N = in_sizes[0] / D;
  const int NB   = (N + BLK - 1) / BLK;
  const int EB   = (E + BLK - 1) / BLK;
  const int EBC  = (E + CHUNK - 1) / CHUNK;
  const int NBKT = (N + (1 << BSH) - 1) >> BSH;   // 196 for N=100K

  char* p = (char*)d_ws;
  auto alloc = [&](size_t bytes) {
    char* q = p;
    p += (bytes + 255) & ~(size_t)255;
    return q;
  };
  int* cnt              = (int*)alloc((size_t)N * 4);
  int* row_ptr          = (int*)alloc((size_t)(N + 1) * 4);
  int* boff             = (int*)alloc((size_t)NB * 4);
  int* bkt              = (int*)alloc((size_t)NBKT * 4);  // counts -> offsets
  int* bcur             = (int*)alloc((size_t)NBKT * 4);  // pass-A run cursors
  unsigned char* maskb  = (unsigned char*)alloc((size_t)E);
  Edge* es              = (Edge*)alloc((size_t)E * 8 + 64);  // +slack for OOB unroll reads
  // union: {es_b + rowb} (build phase) overlap xA (spmm phase; first written iter 1)
  size_t un_sz = (size_t)E * 12 + 512;
  size_t xa_sz = (size_t)N * D * 4;
  char* un = alloc(un_sz > xa_sz ? un_sz : xa_sz);
  Edge* es_b = (Edge*)un;
  int*  rowb = (int*)(un + (((size_t)E * 8 + 255) & ~(size_t)255));
  float* xA  = (float*)un;

  hipMemsetAsync(cnt, 0, (size_t)N * 4, stream);
  k_mask_hist<<<EB, BLK, 0, stream>>>(edge_row, maskb, cnt, E);
  k_block_sum<<<NB, BLK, 0, stream>>>(cnt, boff, N);
  k_bkt_cnt<<<NBKT, 64, 0, stream>>>(cnt, bkt, N);
  k_scan2<<<2, 512, 0, stream>>>(boff, NB, bkt, NBKT, bcur);
  k_write_rowptr<<<NB, BLK, 0, stream>>>(cnt, boff, row_ptr, N, E);
  k_bucket_ms<<<EBC, BLK, 0, stream>>>(edge_row, edge_col, edge_val, maskb,
                                       bcur, es_b, rowb, E, NBKT);
  k_final_scatter<<<NBKT, BLK, 0, stream>>>(es_b, rowb, bkt, row_ptr, es, E);

  const int RPB = BLK / 16;  // rows per block
  const float* src = logits;
  float* dst = out;
  for (int i = 0; i < 5; ++i) {
    k_spmm<<<(N + RPB - 1) / RPB, BLK, 0, stream>>>(row_ptr, es,
                                                    src, logits, dst, N, i);
    src = dst;
    dst = (dst == out) ? xA : out;
  }
}

// Round 9
// 336.931 us; speedup vs baseline: 3.7531x; 1.1477x over previous
//
#include <hip/hip_runtime.h>
#include <stdint.h>
#include <stddef.h>

#define D 48
#define BLK 256
#define BLD 512               // k_build block size (== rows per bucket)
#define BSH 9                 // bucket = row >> 9 (512 rows/bucket)
#define NBKT_MAX 256
#define EPT 16                // edges per thread in multisplit
#define CHUNK (BLK * EPT)     // 4096 edges per block

// ---------------- JAX threefry2x32 (20 rounds), constexpr so keys fold ----------------
struct U2 { uint32_t a, b; };

__host__ __device__ constexpr U2 tf2x32(uint32_t k0, uint32_t k1, uint32_t c0, uint32_t c1) {
  uint32_t ks2 = k0 ^ k1 ^ 0x1BD11BDAu;
  uint32_t x0 = c0 + k0, x1 = c1 + k1;
#define TFR(r) x0 += x1; x1 = (x1 << (r)) | (x1 >> (32 - (r))); x1 ^= x0;
  TFR(13) TFR(15) TFR(26) TFR(6)
  x0 += k1; x1 += ks2 + 1u;
  TFR(17) TFR(29) TFR(16) TFR(24)
  x0 += ks2; x1 += k0 + 2u;
  TFR(13) TFR(15) TFR(26) TFR(6)
  x0 += k0; x1 += k1 + 3u;
  TFR(17) TFR(29) TFR(16) TFR(24)
  x0 += k1; x1 += ks2 + 4u;
  TFR(13) TFR(15) TFR(26) TFR(6)
  x0 += ks2; x1 += k0 + 5u;
#undef TFR
  return U2{x0, x1};
}

// cm = col | (mask5 << 20); col < 2^20 (N = 100K), mask bit i = kept in iter i
struct __align__(8) Edge { uint32_t cm; float val; };

// Bucket counts via LDS hist: one global atomic per (block,bucket) — 77K total
// (vs 1.6M per-row atomics that cost 67µs + 51MB write thrash in R7's mask_hist).
__global__ __launch_bounds__(BLK) void k_bkt_hist(
    const int* __restrict__ erow, int* __restrict__ bkt, int E, int nbkt) {
  __shared__ int h[NBKT_MAX];
  int t = threadIdx.x;
  int j0 = blockIdx.x * CHUNK;
  for (int i = t; i < nbkt; i += BLK) h[i] = 0;
  __syncthreads();
#pragma unroll
  for (int k = 0; k < EPT; ++k) {
    int j = j0 + k * BLK + t;
    if (j < E) atomicAdd(&h[erow[j] >> BSH], 1);
  }
  __syncthreads();
  for (int i = t; i < nbkt; i += BLK)
    if (h[i]) atomicAdd(&bkt[i], h[i]);
}

// 1 block: exclusive-scan bkt[0..nbkt) in place, copy to bcur, write sentinels.
__global__ __launch_bounds__(BLK) void k_scan_bkt(
    int* __restrict__ bkt, int* __restrict__ bcur, int* __restrict__ row_ptr,
    int nbkt, int N, int E) {
  __shared__ int s[BLK];
  int t = threadIdx.x;
  int v = (t < nbkt) ? bkt[t] : 0;
  s[t] = v;
  __syncthreads();
  for (int off = 1; off < BLK; off <<= 1) {
    int u = (t >= off) ? s[t - off] : 0;
    __syncthreads();
    s[t] += u;
    __syncthreads();
  }
  if (t < nbkt) {
    int excl = s[t] - v;
    bkt[t]  = excl;
    bcur[t] = excl;
  }
  if (t == 0) { bkt[nbkt] = E; row_ptr[N] = E; }
}

// Pass A: LDS-multisplit bucket partition, threefry mask computed INLINE
// (mask depends only on edge index; ~10µs VALU hides under 32MB streaming).
__global__ __launch_bounds__(BLK) void k_bucket_ms(
    const int* __restrict__ erow, const int* __restrict__ ecol,
    const float* __restrict__ eval,
    int* __restrict__ bcur, Edge* __restrict__ es_b, int* __restrict__ rowb,
    int E, int nbkt) {
  __shared__ int h[NBKT_MAX];
  __shared__ int base[NBKT_MAX];
  constexpr U2 K0 = tf2x32(0u, 42u, 0u, 0u);
  constexpr U2 K1 = tf2x32(0u, 42u, 0u, 1u);
  constexpr U2 K2 = tf2x32(0u, 42u, 0u, 2u);
  constexpr U2 K3 = tf2x32(0u, 42u, 0u, 3u);
  constexpr U2 K4 = tf2x32(0u, 42u, 0u, 4u);
  int t = threadIdx.x;
  int j0 = blockIdx.x * CHUNK;
  for (int i = t; i < nbkt; i += BLK) h[i] = 0;
  __syncthreads();
#pragma unroll
  for (int k = 0; k < EPT; ++k) {
    int j = j0 + k * BLK + t;
    if (j < E) atomicAdd(&h[erow[j] >> BSH], 1);
  }
  __syncthreads();
  for (int i = t; i < nbkt; i += BLK)
    base[i] = h[i] ? atomicAdd(&bcur[i], h[i]) : 0;
  __syncthreads();
  for (int i = t; i < nbkt; i += BLK) h[i] = 0;
  __syncthreads();
#pragma unroll
  for (int k = 0; k < EPT; ++k) {
    int j = j0 + k * BLK + t;
    if (j >= E) continue;
    int row = erow[j];
    int b = row >> BSH;
    uint32_t uj = (uint32_t)j;
    unsigned m = 0;
    U2 r;
    r = tf2x32(K0.a, K0.b, 0u, uj); m |= ((((r.a ^ r.b) >> 31) ^ 1u) << 0);
    r = tf2x32(K1.a, K1.b, 0u, uj); m |= ((((r.a ^ r.b) >> 31) ^ 1u) << 1);
    r = tf2x32(K2.a, K2.b, 0u, uj); m |= ((((r.a ^ r.b) >> 31) ^ 1u) << 2);
    r = tf2x32(K3.a, K3.b, 0u, uj); m |= ((((r.a ^ r.b) >> 31) ^ 1u) << 3);
    r = tf2x32(K4.a, K4.b, 0u, uj); m |= ((((r.a ^ r.b) >> 31) ^ 1u) << 4);
    int slot = atomicAdd(&h[b], 1);
    int p = base[b] + slot;
    Edge eg;
    eg.cm  = (uint32_t)ecol[j] | (m << 20);
    eg.val = eval[j] * 2.0f;  // 1/keep = 2
    es_b[p] = eg;
    rowb[p] = row;
  }
}

// Pass B: one block per bucket. Count the bucket's 512 rows in LDS, LDS-scan
// -> row_ptr written directly (scan value IS the scatter cursor), then scatter.
// Zero global atomics; all writes in the bucket's private CSR window.
__global__ __launch_bounds__(BLD) void k_build(
    const Edge* __restrict__ es_b, const int* __restrict__ rowb,
    const int* __restrict__ bkt_off, int* __restrict__ row_ptr,
    Edge* __restrict__ es, int N) {
  __shared__ int lc[1 << BSH];
  __shared__ int sc[1 << BSH];
  int b = blockIdx.x, t = threadIdx.x;
  int s = bkt_off[b], e = bkt_off[b + 1];
  int rbase = b << BSH;
  lc[t] = 0;
  __syncthreads();
  for (int j = s + t; j < e; j += BLD) atomicAdd(&lc[rowb[j] - rbase], 1);
  __syncthreads();
  int v = lc[t];
  sc[t] = v;
  __syncthreads();
  for (int off = 1; off < BLD; off <<= 1) {
    int u = (t >= off) ? sc[t - off] : 0;
    __syncthreads();
    sc[t] += u;
    __syncthreads();
  }
  int excl = sc[t] - v;
  int row = rbase + t;
  if (row < N) row_ptr[row] = s + excl;
  lc[t] = s + excl;             // cursor = exclusive offset
  __syncthreads();
  for (int j = s + t; j < e; j += BLD) {
    int p = atomicAdd(&lc[rowb[j] - rbase], 1);
    es[p] = es_b[j];
  }
}

// 4 rows per wave: 16 lanes/row, each lane owns 3 features.
// Branchless, unroll-8: dropped/OOB edges gather row 0 of x (L1-hot) with val=0.
__global__ __launch_bounds__(BLK) void k_spmm(
    const int* __restrict__ row_ptr, const Edge* __restrict__ es,
    const float* __restrict__ x, const float* __restrict__ logits,
    float* __restrict__ xn, int N, int iter) {
  int t = blockIdx.x * BLK + threadIdx.x;
  int r = t >> 4;            // 16 threads per row
  if (r >= N) return;
  int sl = t & 15;
  int s = row_ptr[r], e = row_ptr[r + 1];
  float a0 = 0.f, a1 = 0.f, a2 = 0.f;
  const float* xb = x + 3 * sl;
  const unsigned shift = 20u + (unsigned)iter;
  for (int k = s; k < e; k += 8) {
#pragma unroll
    for (int i = 0; i < 8; ++i) {
      int kk = k + i;
      // OOB reads (≤7 elems past row end) stay inside d_ws slack; zeroed by `in`.
      bool in = kk < e;
      Edge eg = es[kk];
      bool bit = in && ((eg.cm >> shift) & 1u);
      int c = bit ? (int)(eg.cm & 0xFFFFFu) : 0;
      float v = bit ? eg.val : 0.0f;
      const float* xp = xb + (size_t)c * D;
      a0 = fmaf(v, xp[0], a0);
      a1 = fmaf(v, xp[1], a1);
      a2 = fmaf(v, xp[2], a2);
    }
  }
  size_t o = (size_t)r * D + 3 * sl;
  xn[o + 0] = 0.85f * a0 + 0.15f * logits[o + 0];
  xn[o + 1] = 0.85f * a1 + 0.15f * logits[o + 1];
  xn[o + 2] = 0.85f * a2 + 0.15f * logits[o + 2];
}

extern "C" void kernel_launch(void* const* d_in, const int* in_sizes, int n_in,
                              void* d_out, int out_size, void* d_ws, size_t ws_size,
                              hipStream_t stream) {
  const float* logits   = (const float*)d_in[0];
  const float* edge_val = (const float*)d_in[1];
  const int*   edge_row = (const int*)d_in[2];
  const int*   edge_col = (const int*)d_in[3];
  float* out = (float*)d_out;

  const int E = in_sizes[1];
  const int N = in_sizes[0] / D;
  const int EBC  = (E + CHUNK - 1) / CHUNK;
  const int NBKT = (N + (1 << BSH) - 1) >> BSH;   // 196 for N=100K

  char* p = (char*)d_ws;
  auto alloc = [&](size_t bytes) {
    char* q = p;
    p += (bytes + 255) & ~(size_t)255;
    return q;
  };
  int* row_ptr = (int*)alloc((size_t)(N + 1) * 4);
  int* bkt     = (int*)alloc((size_t)(NBKT + 1) * 4);  // counts -> offsets (+sentinel)
  int* bcur    = (int*)alloc((size_t)NBKT * 4);        // pass-A run cursors
  Edge* es     = (Edge*)alloc((size_t)E * 8 + 64);     // +slack for OOB unroll reads
  // union: {es_b + rowb} (build phase) overlap xA (spmm phase; first written iter 1)
  size_t un_sz = (size_t)E * 12 + 512;
  size_t xa_sz = (size_t)N * D * 4;
  char* un = alloc(un_sz > xa_sz ? un_sz : xa_sz);
  Edge* es_b = (Edge*)un;
  int*  rowb = (int*)(un + (((size_t)E * 8 + 255) & ~(size_t)255));
  float* xA  = (float*)un;

  hipMemsetAsync(bkt, 0, (size_t)(NBKT + 1) * 4, stream);
  k_bkt_hist<<<EBC, BLK, 0, stream>>>(edge_row, bkt, E, NBKT);
  k_scan_bkt<<<1, BLK, 0, stream>>>(bkt, bcur, row_ptr, NBKT, N, E);
  k_bucket_ms<<<EBC, BLK, 0, stream>>>(edge_row, edge_col, edge_val,
                                       bcur, es_b, rowb, E, NBKT);
  k_build<<<NBKT, BLD, 0, stream>>>(es_b, rowb, bkt, row_ptr, es, N);

  const int RPB = BLK / 16;  // rows per block
  const float* src = logits;
  float* dst = out;
  for (int i = 0; i < 5; ++i) {
    k_spmm<<<(N + RPB - 1) / RPB, BLK, 0, stream>>>(row_ptr, es,
                                                    src, logits, dst, N, i);
    src = dst;
    dst = (dst == out) ? xA : out;
  }
}

// Round 11
// 330.857 us; speedup vs baseline: 3.8220x; 1.0184x over previous
//
#include <hip/hip_runtime.h>
#include <stdint.h>
#include <stddef.h>

#define D 48
#define BLK 256               // spmm/scan block
#define BLKA 1024             // pass-A block (hist + multisplit)
#define EPTA 4                // edges per thread in pass A
#define CHUNK (BLKA * EPTA)   // 4096 edges per block
#define BLD 512               // k_build block size (== rows per bucket)
#define BSH 9                 // bucket = row >> 9 (512 rows/bucket)
#define NBKT_MAX 256
#define B97 0x30800000u       // 97 << 23 (val pack bias)

// ---------------- JAX threefry2x32 (20 rounds), constexpr so keys fold ----------------
struct U2 { uint32_t a, b; };

__host__ __device__ constexpr U2 tf2x32(uint32_t k0, uint32_t k1, uint32_t c0, uint32_t c1) {
  uint32_t ks2 = k0 ^ k1 ^ 0x1BD11BDAu;
  uint32_t x0 = c0 + k0, x1 = c1 + k1;
#define TFR(r) x0 += x1; x1 = (x1 << (r)) | (x1 >> (32 - (r))); x1 ^= x0;
  TFR(13) TFR(15) TFR(26) TFR(6)
  x0 += k1; x1 += ks2 + 1u;
  TFR(17) TFR(29) TFR(16) TFR(24)
  x0 += ks2; x1 += k0 + 2u;
  TFR(13) TFR(15) TFR(26) TFR(6)
  x0 += k0; x1 += k1 + 3u;
  TFR(17) TFR(29) TFR(16) TFR(24)
  x0 += k1; x1 += ks2 + 4u;
  TFR(13) TFR(15) TFR(26) TFR(6)
  x0 += ks2; x1 += k0 + 5u;
#undef TFR
  return U2{x0, x1};
}

// cm = col | (mask5 << 20) in bucket stage
struct __align__(8) Edge { uint32_t cm; float val; };

// Total per-bucket counts. 1024 thr x EPT 4: same 4096-edge chunks (keeps the
// global-atomic rate at ~400/addr) but 4x the waves -> occupancy 13% -> ~70%.
__global__ __launch_bounds__(BLKA) void k_bkt_hist(
    const int* __restrict__ erow, int* __restrict__ bkt, int E, int nbkt) {
  __shared__ int h[NBKT_MAX];
  int t = threadIdx.x;
  int j0 = blockIdx.x * CHUNK;
  for (int i = t; i < nbkt; i += BLKA) h[i] = 0;
  __syncthreads();
#pragma unroll
  for (int k = 0; k < EPTA; ++k) {
    int j = j0 + k * BLKA + t;
    if (j < E) atomicAdd(&h[erow[j] >> BSH], 1);
  }
  __syncthreads();
  for (int i = t; i < nbkt; i += BLKA)
    if (h[i]) atomicAdd(&bkt[i], h[i]);
}

// 1 block: exclusive-scan bkt[0..nbkt) in place, copy to bcur, sentinel.
__global__ __launch_bounds__(BLK) void k_scan_bkt(
    int* __restrict__ bkt, int* __restrict__ bcur, int nbkt, int E) {
  __shared__ int s[BLK];
  int t = threadIdx.x;
  int v = (t < nbkt) ? bkt[t] : 0;
  s[t] = v;
  __syncthreads();
  for (int off = 1; off < BLK; off <<= 1) {
    int u = (t >= off) ? s[t - off] : 0;
    __syncthreads();
    s[t] += u;
    __syncthreads();
  }
  if (t < nbkt) {
    int excl = s[t] - v;
    bkt[t]  = excl;
    bcur[t] = excl;
  }
  if (t == 0) bkt[nbkt] = E;
}

// Pass A: LDS-multisplit bucket partition, threefry mask inline; also
// accumulates per-(iter,bucket) kept counts for the compacted segments.
__global__ __launch_bounds__(BLKA) void k_bucket_ms(
    const int* __restrict__ erow, const int* __restrict__ ecol,
    const float* __restrict__ eval,
    int* __restrict__ bcur, int* __restrict__ segcnt,
    Edge* __restrict__ es_b, int* __restrict__ rowb, int E, int nbkt) {
  __shared__ int h[NBKT_MAX];
  __shared__ int base[NBKT_MAX];
  __shared__ int hk[5][NBKT_MAX];
  constexpr U2 K0 = tf2x32(0u, 42u, 0u, 0u);
  constexpr U2 K1 = tf2x32(0u, 42u, 0u, 1u);
  constexpr U2 K2 = tf2x32(0u, 42u, 0u, 2u);
  constexpr U2 K3 = tf2x32(0u, 42u, 0u, 3u);
  constexpr U2 K4 = tf2x32(0u, 42u, 0u, 4u);
  int t = threadIdx.x;
  int j0 = blockIdx.x * CHUNK;
  for (int i = t; i < nbkt; i += BLKA) {
    h[i] = 0;
    for (int q = 0; q < 5; ++q) hk[q][i] = 0;
  }
  __syncthreads();
#pragma unroll
  for (int k = 0; k < EPTA; ++k) {
    int j = j0 + k * BLKA + t;
    if (j < E) atomicAdd(&h[erow[j] >> BSH], 1);
  }
  __syncthreads();
  for (int i = t; i < nbkt; i += BLKA)
    base[i] = h[i] ? atomicAdd(&bcur[i], h[i]) : 0;
  __syncthreads();
  for (int i = t; i < nbkt; i += BLKA) h[i] = 0;
  __syncthreads();
#pragma unroll
  for (int k = 0; k < EPTA; ++k) {
    int j = j0 + k * BLKA + t;
    if (j >= E) continue;
    int row = erow[j];
    int b = row >> BSH;
    uint32_t uj = (uint32_t)j;
    unsigned m = 0;
    U2 r;
    r = tf2x32(K0.a, K0.b, 0u, uj); m |= ((((r.a ^ r.b) >> 31) ^ 1u) << 0);
    r = tf2x32(K1.a, K1.b, 0u, uj); m |= ((((r.a ^ r.b) >> 31) ^ 1u) << 1);
    r = tf2x32(K2.a, K2.b, 0u, uj); m |= ((((r.a ^ r.b) >> 31) ^ 1u) << 2);
    r = tf2x32(K3.a, K3.b, 0u, uj); m |= ((((r.a ^ r.b) >> 31) ^ 1u) << 3);
    r = tf2x32(K4.a, K4.b, 0u, uj); m |= ((((r.a ^ r.b) >> 31) ^ 1u) << 4);
#pragma unroll
    for (int q = 0; q < 5; ++q)
      if ((m >> q) & 1u) atomicAdd(&hk[q][b], 1);
    int slot = atomicAdd(&h[b], 1);
    int p = base[b] + slot;
    Edge eg;
    eg.cm  = (uint32_t)ecol[j] | (m << 20);
    eg.val = eval[j] * 2.0f;  // 1/keep = 2
    es_b[p] = eg;
    rowb[p] = row;
  }
  __syncthreads();
  for (int i = t; i < nbkt; i += BLKA)
    for (int q = 0; q < 5; ++q)
      if (hk[q][i]) atomicAdd(&segcnt[q * nbkt + i], hk[q][i]);
}

// 1 block, 1024 thr: exclusive-scan segcnt[0..5*nbkt) flat (iter-major) in
// place -> segment offsets; slot 5*nbkt = total. Write rp_i[N] sentinels.
__global__ __launch_bounds__(1024) void k_scan_seg(
    int* __restrict__ seg, int* __restrict__ rp5, int nbkt, int N) {
  __shared__ int s[1024];
  int t = threadIdx.x;
  int n = 5 * nbkt;
  int v = (t < n) ? seg[t] : 0;
  s[t] = v;
  __syncthreads();
  for (int off = 1; off < 1024; off <<= 1) {
    int u = (t >= off) ? s[t - off] : 0;
    __syncthreads();
    s[t] += u;
    __syncthreads();
  }
  if (t <= n) seg[t] = s[t] - v;   // exclusive; seg[n] = total
  __syncthreads();
  if (t < 5) rp5[(size_t)t * (N + 1) + N] = seg[(t + 1) * nbkt];
}

// Pass B: one block per bucket. Per-(row,iter) counts in LDS, 5 LDS scans ->
// per-iter row_ptr + cursors; then append each edge to the iter-lists of its
// set mask bits. Entry = col(17b) | pkval(15b custom float, rel err 2^-11).
__global__ __launch_bounds__(BLD) void k_build(
    const Edge* __restrict__ es_b, const int* __restrict__ rowb,
    const int* __restrict__ bkt_off, const int* __restrict__ segoff,
    int* __restrict__ rp5, uint32_t* __restrict__ es_all, int N, int nbkt) {
  __shared__ int lc[5][1 << BSH];
  __shared__ int sc[1 << BSH];
  int b = blockIdx.x, t = threadIdx.x;
  int s = bkt_off[b], e = bkt_off[b + 1];
  int rbase = b << BSH;
#pragma unroll
  for (int i = 0; i < 5; ++i) lc[i][t] = 0;
  __syncthreads();
  for (int j = s + t; j < e; j += BLD) {
    int row = rowb[j] - rbase;
    unsigned m = es_b[j].cm >> 20;
#pragma unroll
    for (int i = 0; i < 5; ++i)
      if ((m >> i) & 1u) atomicAdd(&lc[i][row], 1);
  }
  __syncthreads();
  for (int i = 0; i < 5; ++i) {
    int v = lc[i][t];
    sc[t] = v;
    __syncthreads();
    for (int off = 1; off < BLD; off <<= 1) {
      int u = (t >= off) ? sc[t - off] : 0;
      __syncthreads();
      sc[t] += u;
      __syncthreads();
    }
    int pos = segoff[i * nbkt + b] + sc[t] - v;
    int row = rbase + t;
    if (row < N) rp5[(size_t)i * (N + 1) + row] = pos;
    lc[i][t] = pos;              // cursor
    __syncthreads();
  }
  for (int j = s + t; j < e; j += BLD) {
    int row = rowb[j] - rbase;
    Edge eg = es_b[j];
    unsigned m = eg.cm >> 20;
    uint32_t vb = __float_as_uint(eg.val);
    uint32_t pk = (vb < B97) ? 0u : ((vb - B97 + (1u << 12)) >> 13);
    uint32_t entry = (eg.cm & 0x1FFFFu) | (pk << 17);
#pragma unroll
    for (int i = 0; i < 5; ++i)
      if ((m >> i) & 1u) {
        int p = atomicAdd(&lc[i][row], 1);
        es_all[p] = entry;
      }
  }
}

// 4 rows per wave: 16 lanes/row, each lane owns 3 features. Kept-only list:
// no mask test, avg 8 entries/row -> one unroll-8 batch for most rows.
__global__ __launch_bounds__(BLK) void k_spmm(
    const int* __restrict__ rp, const uint32_t* __restrict__ es_all,
    const float* __restrict__ x, const float* __restrict__ logits,
    float* __restrict__ xn, int N) {
  int t = blockIdx.x * BLK + threadIdx.x;
  int r = t >> 4;            // 16 threads per row
  if (r >= N) return;
  int sl = t & 15;
  int s = rp[r], e = rp[r + 1];
  float a0 = 0.f, a1 = 0.f, a2 = 0.f;
  const float* xb = x + 3 * sl;
  for (int k = s; k < e; k += 8) {
#pragma unroll
    for (int i = 0; i < 8; ++i) {
      int kk = k + i;
      // OOB reads (≤7 past row end) stay inside es_all+slack; zeroed by `in`.
      bool in = kk < e;
      uint32_t u = es_all[kk];
      int c = in ? (int)(u & 0x1FFFFu) : 0;
      uint32_t vb = ((u >> 17) << 13) + B97;
      float v = in ? __uint_as_float(vb) : 0.0f;
      const float* xp = xb + (size_t)c * D;
      a0 = fmaf(v, xp[0], a0);
      a1 = fmaf(v, xp[1], a1);
      a2 = fmaf(v, xp[2], a2);
    }
  }
  size_t o = (size_t)r * D + 3 * sl;
  xn[o + 0] = 0.85f * a0 + 0.15f * logits[o + 0];
  xn[o + 1] = 0.85f * a1 + 0.15f * logits[o + 1];
  xn[o + 2] = 0.85f * a2 + 0.15f * logits[o + 2];
}

extern "C" void kernel_launch(void* const* d_in, const int* in_sizes, int n_in,
                              void* d_out, int out_size, void* d_ws, size_t ws_size,
                              hipStream_t stream) {
  const float* logits   = (const float*)d_in[0];
  const float* edge_val = (const float*)d_in[1];
  const int*   edge_row = (const int*)d_in[2];
  const int*   edge_col = (const int*)d_in[3];
  float* out = (float*)d_out;

  const int E = in_sizes[1];
  const int N = in_sizes[0] / D;
  const int EBC  = (E + CHUNK - 1) / CHUNK;
  const int NBKT = (N + (1 << BSH) - 1) >> BSH;   // 196 for N=100K

  char* p = (char*)d_ws;
  auto alloc = [&](size_t bytes) {
    char* q = p;
    p += (bytes + 255) & ~(size_t)255;
    return q;
  };
  int* rp5     = (int*)alloc((size_t)5 * (N + 1) * 4);
  int* bkt     = (int*)alloc((size_t)(NBKT + 1) * 4);   // counts -> offsets
  int* bcur    = (int*)alloc((size_t)NBKT * 4);         // pass-A run cursors
  int* segcnt  = (int*)alloc((size_t)(5 * NBKT + 1) * 4); // counts -> offsets (+total)
  // kept entries: deterministic ~E*2.5; slack 64K entries
  uint32_t* es_all = (uint32_t*)alloc(((size_t)E * 5 / 2 + 65536) * 4);
  // union: {es_b + rowb} (build phase) overlap xA (spmm phase; first written iter 1)
  size_t un_sz = (size_t)E * 12 + 512;
  size_t xa_sz = (size_t)N * D * 4;
  char* un = alloc(un_sz > xa_sz ? un_sz : xa_sz);
  Edge* es_b = (Edge*)un;
  int*  rowb = (int*)(un + (((size_t)E * 8 + 255) & ~(size_t)255));
  float* xA  = (float*)un;

  hipMemsetAsync(bkt, 0, (size_t)(NBKT + 1) * 4, stream);
  hipMemsetAsync(segcnt, 0, (size_t)(5 * NBKT + 1) * 4, stream);
  k_bkt_hist<<<EBC, BLKA, 0, stream>>>(edge_row, bkt, E, NBKT);
  k_scan_bkt<<<1, BLK, 0, stream>>>(bkt, bcur, NBKT, E);
  k_bucket_ms<<<EBC, BLKA, 0, stream>>>(edge_row, edge_col, edge_val,
                                        bcur, segcnt, es_b, rowb, E, NBKT);
  k_scan_seg<<<1, 1024, 0, stream>>>(segcnt, rp5, NBKT, N);
  k_build<<<NBKT, BLD, 0, stream>>>(es_b, rowb, bkt, segcnt, rp5, es_all, N, NBKT);

  const int RPB = BLK / 16;  // rows per block
  const float* src = logits;
  float* dst = out;
  for (int i = 0; i < 5; ++i) {
    k_spmm<<<(N + RPB - 1) / RPB, BLK, 0, stream>>>(rp5 + (size_t)i * (N + 1),
                                                    es_all, src, logits, dst, N);
    src = dst;
    dst = (dst == out) ? xA : out;
  }
}

// Round 16
// 308.299 us; speedup vs baseline: 4.1016x; 1.0732x over previous
//
#include <hip/hip_runtime.h>
#include <stdint.h>
#include <stddef.h>

#define D 48
#define BLK 256               // spmm/scan/prep block
#define BLKA 1024             // pass-A block (hist + multisplit)
#define EPTA 4                // edges per thread in pass A
#define CHUNK (BLKA * EPTA)   // 4096 edges per block
#define BLD 512               // k_build block size (== rows per bucket)
#define BSH 9                 // bucket = row >> 9 (512 rows/bucket)
#define NBKT_MAX 256
#define B97 0x30800000u       // 97 << 23 (val pack bias)

// ---------------- JAX threefry2x32 (20 rounds), constexpr so keys fold ----------------
struct U2 { uint32_t a, b; };

__host__ __device__ constexpr U2 tf2x32(uint32_t k0, uint32_t k1, uint32_t c0, uint32_t c1) {
  uint32_t ks2 = k0 ^ k1 ^ 0x1BD11BDAu;
  uint32_t x0 = c0 + k0, x1 = c1 + k1;
#define TFR(r) x0 += x1; x1 = (x1 << (r)) | (x1 >> (32 - (r))); x1 ^= x0;
  TFR(13) TFR(15) TFR(26) TFR(6)
  x0 += k1; x1 += ks2 + 1u;
  TFR(17) TFR(29) TFR(16) TFR(24)
  x0 += ks2; x1 += k0 + 2u;
  TFR(13) TFR(15) TFR(26) TFR(6)
  x0 += k0; x1 += k1 + 3u;
  TFR(17) TFR(29) TFR(16) TFR(24)
  x0 += k1; x1 += ks2 + 4u;
  TFR(13) TFR(15) TFR(26) TFR(6)
  x0 += ks2; x1 += k0 + 5u;
#undef TFR
  return U2{x0, x1};
}

__device__ __forceinline__ unsigned mask5_of(uint32_t uj) {
  constexpr U2 K0 = tf2x32(0u, 42u, 0u, 0u);
  constexpr U2 K1 = tf2x32(0u, 42u, 0u, 1u);
  constexpr U2 K2 = tf2x32(0u, 42u, 0u, 2u);
  constexpr U2 K3 = tf2x32(0u, 42u, 0u, 3u);
  constexpr U2 K4 = tf2x32(0u, 42u, 0u, 4u);
  unsigned m = 0;
  U2 r;
  r = tf2x32(K0.a, K0.b, 0u, uj); m |= ((((r.a ^ r.b) >> 31) ^ 1u) << 0);
  r = tf2x32(K1.a, K1.b, 0u, uj); m |= ((((r.a ^ r.b) >> 31) ^ 1u) << 1);
  r = tf2x32(K2.a, K2.b, 0u, uj); m |= ((((r.a ^ r.b) >> 31) ^ 1u) << 2);
  r = tf2x32(K3.a, K3.b, 0u, uj); m |= ((((r.a ^ r.b) >> 31) ^ 1u) << 3);
  r = tf2x32(K4.a, K4.b, 0u, uj); m |= ((((r.a ^ r.b) >> 31) ^ 1u) << 4);
  return m;
}

__device__ __forceinline__ uint32_t rne16(float f) {
  uint32_t u = __float_as_uint(f);
  return (u + 0x7FFFu + ((u >> 16) & 1u)) >> 16;
}
__device__ __forceinline__ uint32_t pk2(float a, float b) {
  return rne16(a) | (rne16(b) << 16);
}

// cm = col | (mask5 << 20) in bucket stage
struct __align__(8) Edge { uint32_t cm; float val; };

// logits f32 -> packed bf16 (RNE), 4 elems/thread
__global__ __launch_bounds__(BLK) void k_prep(
    const float4* __restrict__ in, uint2* __restrict__ outp, int n4) {
  int i = blockIdx.x * BLK + threadIdx.x;
  if (i >= n4) return;
  float4 f = in[i];
  outp[i] = make_uint2(pk2(f.x, f.y), pk2(f.z, f.w));
}

// Per-bucket totals AND per-(iter,bucket) kept counts (threefry inline; mask
// depends only on edge index). hk padded +1 so the 5 q-strided atomics land
// in different banks (257 % 32 = 1).
__global__ __launch_bounds__(BLKA) void k_bkt_hist(
    const int* __restrict__ erow, int* __restrict__ bkt,
    int* __restrict__ segcnt, int E, int nbkt) {
  __shared__ int h[NBKT_MAX];
  __shared__ int hk[5][NBKT_MAX + 1];
  int t = threadIdx.x;
  int j0 = blockIdx.x * CHUNK;
  for (int i = t; i < nbkt; i += BLKA) {
    h[i] = 0;
    for (int q = 0; q < 5; ++q) hk[q][i] = 0;
  }
  __syncthreads();
#pragma unroll
  for (int k = 0; k < EPTA; ++k) {
    int j = j0 + k * BLKA + t;
    if (j < E) {
      int b = erow[j] >> BSH;
      atomicAdd(&h[b], 1);
      unsigned m = mask5_of((uint32_t)j);
#pragma unroll
      for (int q = 0; q < 5; ++q)
        if ((m >> q) & 1u) atomicAdd(&hk[q][b], 1);
    }
  }
  __syncthreads();
  for (int i = t; i < nbkt; i += BLKA) {
    if (h[i]) atomicAdd(&bkt[i], h[i]);
    for (int q = 0; q < 5; ++q)
      if (hk[q][i]) atomicAdd(&segcnt[q * nbkt + i], hk[q][i]);
  }
}

// 1 block: exclusive-scan bkt[0..nbkt) in place, copy to bcur, sentinel.
__global__ __launch_bounds__(BLK) void k_scan_bkt(
    int* __restrict__ bkt, int* __restrict__ bcur, int nbkt, int E) {
  __shared__ int s[BLK];
  int t = threadIdx.x;
  int v = (t < nbkt) ? bkt[t] : 0;
  s[t] = v;
  __syncthreads();
  for (int off = 1; off < BLK; off <<= 1) {
    int u = (t >= off) ? s[t - off] : 0;
    __syncthreads();
    s[t] += u;
    __syncthreads();
  }
  if (t < nbkt) {
    int excl = s[t] - v;
    bkt[t]  = excl;
    bcur[t] = excl;
  }
  if (t == 0) bkt[nbkt] = E;
}

// Pass A: LDS-multisplit bucket partition, threefry mask inline (packed in cm).
__global__ __launch_bounds__(BLKA) void k_bucket_ms(
    const int* __restrict__ erow, const int* __restrict__ ecol,
    const float* __restrict__ eval,
    int* __restrict__ bcur, Edge* __restrict__ es_b, int* __restrict__ rowb,
    int E, int nbkt) {
  __shared__ int h[NBKT_MAX];
  __shared__ int base[NBKT_MAX];
  int t = threadIdx.x;
  int j0 = blockIdx.x * CHUNK;
  for (int i = t; i < nbkt; i += BLKA) h[i] = 0;
  __syncthreads();
#pragma unroll
  for (int k = 0; k < EPTA; ++k) {
    int j = j0 + k * BLKA + t;
    if (j < E) atomicAdd(&h[erow[j] >> BSH], 1);
  }
  __syncthreads();
  for (int i = t; i < nbkt; i += BLKA)
    base[i] = h[i] ? atomicAdd(&bcur[i], h[i]) : 0;
  __syncthreads();
  for (int i = t; i < nbkt; i += BLKA) h[i] = 0;
  __syncthreads();
#pragma unroll
  for (int k = 0; k < EPTA; ++k) {
    int j = j0 + k * BLKA + t;
    if (j >= E) continue;
    int row = erow[j];
    int b = row >> BSH;
    unsigned m = mask5_of((uint32_t)j);
    int slot = atomicAdd(&h[b], 1);
    int p = base[b] + slot;
    Edge eg;
    eg.cm  = (uint32_t)ecol[j] | (m << 20);
    eg.val = eval[j] * 2.0f;  // 1/keep = 2
    es_b[p] = eg;
    rowb[p] = row;
  }
}

// 1 block, 1024 thr: exclusive-scan segcnt[0..5*nbkt) flat (iter-major) in
// place -> segment offsets; slot 5*nbkt = total. Write rp_i[N] sentinels.
__global__ __launch_bounds__(1024) void k_scan_seg(
    int* __restrict__ seg, int* __restrict__ rp5, int nbkt, int N) {
  __shared__ int s[1024];
  int t = threadIdx.x;
  int n = 5 * nbkt;
  int v = (t < n) ? seg[t] : 0;
  s[t] = v;
  __syncthreads();
  for (int off = 1; off < 1024; off <<= 1) {
    int u = (t >= off) ? s[t - off] : 0;
    __syncthreads();
    s[t] += u;
    __syncthreads();
  }
  if (t <= n) seg[t] = s[t] - v;   // exclusive; seg[n] = total
  __syncthreads();
  if (t < 5) rp5[(size_t)t * (N + 1) + N] = seg[(t + 1) * nbkt];
}

// Pass B: one block per bucket. Per-(row,iter) counts in LDS, 5 LDS scans ->
// per-iter row_ptr + cursors; then append each edge to the iter-lists of its
// set mask bits. Entry = col(17b) | pkval(15b custom float, rel err 2^-11).
__global__ __launch_bounds__(BLD) void k_build(
    const Edge* __restrict__ es_b, const int* __restrict__ rowb,
    const int* __restrict__ bkt_off, const int* __restrict__ segoff,
    int* __restrict__ rp5, uint32_t* __restrict__ es_all, int N, int nbkt) {
  __shared__ int lc[5][1 << BSH];
  __shared__ int sc[1 << BSH];
  int b = blockIdx.x, t = threadIdx.x;
  int s = bkt_off[b], e = bkt_off[b + 1];
  int rbase = b << BSH;
#pragma unroll
  for (int i = 0; i < 5; ++i) lc[i][t] = 0;
  __syncthreads();
  for (int j = s + t; j < e; j += BLD) {
    int row = rowb[j] - rbase;
    unsigned m = es_b[j].cm >> 20;
#pragma unroll
    for (int i = 0; i < 5; ++i)
      if ((m >> i) & 1u) atomicAdd(&lc[i][row], 1);
  }
  __syncthreads();
  for (int i = 0; i < 5; ++i) {
    int v = lc[i][t];
    sc[t] = v;
    __syncthreads();
    for (int off = 1; off < BLD; off <<= 1) {
      int u = (t >= off) ? sc[t - off] : 0;
      __syncthreads();
      sc[t] += u;
      __syncthreads();
    }
    int pos = segoff[i * nbkt + b] + sc[t] - v;
    int row = rbase + t;
    if (row < N) rp5[(size_t)i * (N + 1) + row] = pos;
    lc[i][t] = pos;              // cursor
    __syncthreads();
  }
  for (int j = s + t; j < e; j += BLD) {
    int row = rowb[j] - rbase;
    Edge eg = es_b[j];
    unsigned m = eg.cm >> 20;
    uint32_t vb = __float_as_uint(eg.val);
    uint32_t pk = (vb < B97) ? 0u : ((vb - B97 + (1u << 12)) >> 13);
    uint32_t entry = (eg.cm & 0x1FFFFu) | (pk << 17);
#pragma unroll
    for (int i = 0; i < 5; ++i)
      if ((m >> i) & 1u) {
        int p = atomicAdd(&lc[i][row], 1);
        es_all[p] = entry;
      }
  }
}

// 8 lanes/row, 6 bf16 features/lane (row = 24 uints = 96B). Kept-only list.
// Branchless unroll-8; dropped/OOB lanes gather row 0 (L1-hot) with v=0.
// FINAL=1 writes f32 to d_out; else packed-bf16 (RNE) to xd.
template<int FINAL>
__global__ __launch_bounds__(BLK) void k_spmm_b(
    const int* __restrict__ rp, const uint32_t* __restrict__ es_all,
    const uint32_t* __restrict__ xs, const uint32_t* __restrict__ lb,
    uint32_t* __restrict__ xd, float* __restrict__ xf, int N) {
  int t = blockIdx.x * BLK + threadIdx.x;
  int r = t >> 3;            // 8 threads per row
  if (r >= N) return;
  int sl = t & 7;
  int s = rp[r], e = rp[r + 1];
  float a0 = 0.f, a1 = 0.f, a2 = 0.f, a3 = 0.f, a4 = 0.f, a5 = 0.f;
  const uint32_t* xb = xs + 3 * sl;
  for (int k = s; k < e; k += 8) {
#pragma unroll
    for (int i = 0; i < 8; ++i) {
      int kk = k + i;
      // OOB reads (≤7 past row end) stay inside es_all+slack; zeroed by `in`.
      bool in = kk < e;
      uint32_t u = es_all[kk];
      int c = in ? (int)(u & 0x1FFFFu) : 0;
      uint32_t vb = ((u >> 17) << 13) + B97;
      float v = in ? __uint_as_float(vb) : 0.0f;
      const uint32_t* xp = xb + (size_t)c * 24;
      uint32_t u0 = xp[0], u1 = xp[1], u2 = xp[2];
      a0 = fmaf(v, __uint_as_float(u0 << 16), a0);
      a1 = fmaf(v, __uint_as_float(u0 & 0xFFFF0000u), a1);
      a2 = fmaf(v, __uint_as_float(u1 << 16), a2);
      a3 = fmaf(v, __uint_as_float(u1 & 0xFFFF0000u), a3);
      a4 = fmaf(v, __uint_as_float(u2 << 16), a4);
      a5 = fmaf(v, __uint_as_float(u2 & 0xFFFF0000u), a5);
    }
  }
  int base = r * 24 + 3 * sl;
  uint32_t l0 = lb[base], l1 = lb[base + 1], l2 = lb[base + 2];
  float o0 = 0.85f * a0 + 0.15f * __uint_as_float(l0 << 16);
  float o1 = 0.85f * a1 + 0.15f * __uint_as_float(l0 & 0xFFFF0000u);
  float o2 = 0.85f * a2 + 0.15f * __uint_as_float(l1 << 16);
  float o3 = 0.85f * a3 + 0.15f * __uint_as_float(l1 & 0xFFFF0000u);
  float o4 = 0.85f * a4 + 0.15f * __uint_as_float(l2 << 16);
  float o5 = 0.85f * a5 + 0.15f * __uint_as_float(l2 & 0xFFFF0000u);
  if (FINAL) {
    size_t ob = (size_t)r * D + 6 * sl;
    xf[ob + 0] = o0; xf[ob + 1] = o1; xf[ob + 2] = o2;
    xf[ob + 3] = o3; xf[ob + 4] = o4; xf[ob + 5] = o5;
  } else {
    xd[base]     = pk2(o0, o1);
    xd[base + 1] = pk2(o2, o3);
    xd[base + 2] = pk2(o4, o5);
  }
}

extern "C" void kernel_launch(void* const* d_in, const int* in_sizes, int n_in,
                              void* d_out, int out_size, void* d_ws, size_t ws_size,
                              hipStream_t stream) {
  const float* logits   = (const float*)d_in[0];
  const float* edge_val = (const float*)d_in[1];
  const int*   edge_row = (const int*)d_in[2];
  const int*   edge_col = (const int*)d_in[3];
  float* out = (float*)d_out;

  const int E = in_sizes[1];
  const int N = in_sizes[0] / D;
  const int EBC  = (E + CHUNK - 1) / CHUNK;
  const int NBKT = (N + (1 << BSH) - 1) >> BSH;   // 196 for N=100K

  char* p = (char*)d_ws;
  auto alloc = [&](size_t bytes) {
    char* q = p;
    p += (bytes + 255) & ~(size_t)255;
    return q;
  };
  int* rp5     = (int*)alloc((size_t)5 * (N + 1) * 4);
  int* bkt     = (int*)alloc((size_t)(NBKT + 1) * 4);     // counts -> offsets
  int* bcur    = (int*)alloc((size_t)NBKT * 4);           // pass-A run cursors
  int* segcnt  = (int*)alloc((size_t)(5 * NBKT + 1) * 4); // counts -> offsets (+total)
  // kept entries: ~E*2.5 expected; 64K-entry slack covers fluctuation + OOB reads
  uint32_t* es_all = (uint32_t*)alloc(((size_t)E * 5 / 2 + 65536) * 4);
  uint32_t* lb     = (uint32_t*)alloc((size_t)N * D * 2); // bf16 logits (own buffer)
  // union: {es_b + rowb} (build phase) overlap {xb0,xb1} (spmm ping-pong)
  size_t un_sz = (size_t)E * 12 + 512;
  size_t xx_sz = (size_t)N * D * 4 + 512;
  char* un = alloc(un_sz > xx_sz ? un_sz : xx_sz);
  Edge* es_b = (Edge*)un;
  int*  rowb = (int*)(un + (((size_t)E * 8 + 255) & ~(size_t)255));
  uint32_t* xb0 = (uint32_t*)un;
  uint32_t* xb1 = (uint32_t*)(un + (((size_t)N * D * 2 + 255) & ~(size_t)255));

  hipMemsetAsync(bkt, 0, (size_t)(NBKT + 1) * 4, stream);
  hipMemsetAsync(segcnt, 0, (size_t)(5 * NBKT + 1) * 4, stream);
  k_prep<<<(N * D / 4 + BLK - 1) / BLK, BLK, 0, stream>>>(
      (const float4*)logits, (uint2*)lb, N * D / 4);
  k_bkt_hist<<<EBC, BLKA, 0, stream>>>(edge_row, bkt, segcnt, E, NBKT);
  k_scan_bkt<<<1, BLK, 0, stream>>>(bkt, bcur, NBKT, E);
  k_bucket_ms<<<EBC, BLKA, 0, stream>>>(edge_row, edge_col, edge_val,
                                        bcur, es_b, rowb, E, NBKT);
  k_scan_seg<<<1, 1024, 0, stream>>>(segcnt, rp5, NBKT, N);
  k_build<<<NBKT, BLD, 0, stream>>>(es_b, rowb, bkt, segcnt, rp5, es_all, N, NBKT);

  const int RPB = BLK / 8;   // rows per block
  const int GB  = (N + RPB - 1) / RPB;
  // iter 0: src = lb (x0 == logits)
  k_spmm_b<0><<<GB, BLK, 0, stream>>>(rp5 + 0 * (size_t)(N + 1), es_all, lb, lb, xb0, nullptr, N);
  k_spmm_b<0><<<GB, BLK, 0, stream>>>(rp5 + 1 * (size_t)(N + 1), es_all, xb0, lb, xb1, nullptr, N);
  k_spmm_b<0><<<GB, BLK, 0, stream>>>(rp5 + 2 * (size_t)(N + 1), es_all, xb1, lb, xb0, nullptr, N);
  k_spmm_b<0><<<GB, BLK, 0, stream>>>(rp5 + 3 * (size_t)(N + 1), es_all, xb0, lb, xb1, nullptr, N);
  k_spmm_b<1><<<GB, BLK, 0, stream>>>(rp5 + 4 * (size_t)(N + 1), es_all, xb1, lb, nullptr, out, N);
}